// Round 1
// baseline (110.745 us; speedup 1.0000x reference)
//
#include <hip/hip_runtime.h>
#include <stdint.h>

#define NR 8192
#define D 256
#define LOG2E 1.4426950408889634f
#define BM 128
#define BK 32
#define NT_SS 2080      // 64*65/2 lower-triangle tiles per symmetric block
#define NT_TOT 8256     // 2*2080 + 4096

typedef __attribute__((ext_vector_type(8))) short short8;
typedef __attribute__((ext_vector_type(4))) float f32x4;

#if __has_builtin(__builtin_amdgcn_exp2f)
#define EXP2F(x) __builtin_amdgcn_exp2f(x)
#else
#define EXP2F(x) exp2f(x)
#endif

typedef __attribute__((address_space(1))) const void gvoid;
typedef __attribute__((address_space(3))) void lvoid;

__device__ __forceinline__ void gload16(const void* g, void* l) {
    // async global->LDS, 16B/lane; LDS dest is wave-uniform base + lane*16
    __builtin_amdgcn_global_load_lds((gvoid*)(uintptr_t)g, (lvoid*)(uintptr_t)l,
                                     16, 0, 0);
}

__device__ __forceinline__ unsigned short f2bf(float f) {
    uint32_t u = __float_as_uint(f);
    u += 0x7fffu + ((u >> 16) & 1u);   // RNE; inputs are finite Gaussians, no NaN
    return (unsigned short)(u >> 16);
}
__device__ __forceinline__ float bf2f(unsigned short h) {
    return __uint_as_float(((uint32_t)h) << 16);
}

// ---------------- kernel 1: f32 -> bf16 copies + row norms (from bf16 values)
__global__ void prep_kernel(const float* __restrict__ src, const float* __restrict__ tgt,
                            unsigned short* __restrict__ Sb, unsigned short* __restrict__ Tb,
                            float* __restrict__ nS, float* __restrict__ nT) {
    int wid = threadIdx.x >> 6, lane = threadIdx.x & 63;
    int row = blockIdx.x * 4 + wid;            // 0..16383
    const float* in; unsigned short* ob; float* on; int r;
    if (row < NR) { in = src; ob = Sb; on = nS; r = row; }
    else         { in = tgt; ob = Tb; on = nT; r = row - NR; }

    const float4* inr = (const float4*)(in + (size_t)r * D);
    float4 v = inr[lane];                       // 256 cols / 64 lanes = 4 f32
    unsigned short b0 = f2bf(v.x), b1 = f2bf(v.y), b2 = f2bf(v.z), b3 = f2bf(v.w);
    float f0 = bf2f(b0), f1 = bf2f(b1), f2 = bf2f(b2), f3 = bf2f(b3);
    float sq = f0 * f0 + f1 * f1 + f2 * f2 + f3 * f3;

    ushort4 pack = make_ushort4(b0, b1, b2, b3);
    *(ushort4*)(ob + (size_t)r * D + lane * 4) = pack;

    #pragma unroll
    for (int o = 32; o > 0; o >>= 1) sq += __shfl_xor(sq, o, 64);
    if (lane == 0) on[r] = -0.5f * LOG2E * sq;  // b_i = -(log2e/2)*||x_i||^2
}

// ---------------- kernel 2: fused tile GEMM + exp epilogue + tile reduction
__global__ __launch_bounds__(256) void mmd_tiles(
    const unsigned short* __restrict__ Sb, const unsigned short* __restrict__ Tb,
    const float* __restrict__ nS, const float* __restrict__ nT,
    float* __restrict__ parts)
{
    __shared__ unsigned short As[BM][BK];   // 8 KB
    __shared__ unsigned short Bs[BM][BK];   // 8 KB
    __shared__ float red[4];

    int bid = blockIdx.x;
    const unsigned short *Ab, *Bb; const float *nA, *nB; float wgt;
    int ti, tj;
    {
        int idx = bid;
        if (bid < 2 * NT_SS) {
            if (bid >= NT_SS) idx -= NT_SS;
            int t = (int)((sqrtf(8.0f * (float)idx + 1.0f) - 1.0f) * 0.5f);
            while ((t + 1) * (t + 2) / 2 <= idx) ++t;
            while (t * (t + 1) / 2 > idx) --t;
            ti = t; tj = idx - t * (t + 1) / 2;          // tj <= ti
            if (bid < NT_SS) { Ab = Sb; Bb = Sb; nA = nS; nB = nS; }
            else             { Ab = Tb; Bb = Tb; nA = nT; nB = nT; }
            wgt = (ti == tj) ? 1.0f : 2.0f;              // symmetric double-count
        } else {
            idx = bid - 2 * NT_SS;
            ti = idx >> 6; tj = idx & 63;
            Ab = Sb; Bb = Tb; nA = nS; nB = nT;
            wgt = -2.0f;                                  // -2 * mean(s,t)
        }
    }
    const int rowBase = ti * BM, colBase = tj * BM;

    const int tid = threadIdx.x;
    const int wid = tid >> 6, lane = tid & 63;
    const int wr = wid >> 1, wc = wid & 1;               // 2x2 waves, 64x64 each

    f32x4 acc[4][4];
    #pragma unroll
    for (int m = 0; m < 4; ++m)
        #pragma unroll
        for (int n = 0; n < 4; ++n) acc[m][n] = (f32x4){0.f, 0.f, 0.f, 0.f};

    const int lr = lane >> 2;            // staging: row within 16-row chunk
    const int lc = (lane & 3) * 8;       // staging: col element offset

    for (int kt = 0; kt < D / BK; ++kt) {
        const int kk = kt * BK;
        #pragma unroll
        for (int c = 0; c < 2; ++c) {
            int q = wid + 4 * c;         // 16-row chunk index 0..7
            gload16(Ab + (size_t)(rowBase + q * 16 + lr) * D + kk + lc, &As[q * 16][0]);
            gload16(Bb + (size_t)(colBase + q * 16 + lr) * D + kk + lc, &Bs[q * 16][0]);
        }
        __syncthreads();                 // drains vmcnt before barrier

        const int fr = lane & 15, ko = (lane >> 4) * 8;
        short8 af[4], bfv[4];
        #pragma unroll
        for (int m = 0; m < 4; ++m) af[m]  = *(const short8*)&As[wr * 64 + m * 16 + fr][ko];
        #pragma unroll
        for (int n = 0; n < 4; ++n) bfv[n] = *(const short8*)&Bs[wc * 64 + n * 16 + fr][ko];
        #pragma unroll
        for (int m = 0; m < 4; ++m)
            #pragma unroll
            for (int n = 0; n < 4; ++n)
                acc[m][n] = __builtin_amdgcn_mfma_f32_16x16x32_bf16(af[m], bfv[n], acc[m][n], 0, 0, 0);
        __syncthreads();
    }

    // epilogue: u = exp(-l2/2) = exp2(log2e*xy + bx_i + cy_j); contrib = u + u^2
    float lsum = 0.0f;
    {
        const int fr = lane & 15, fq = lane >> 4;
        float cy[4]; f32x4 bx[4];
        #pragma unroll
        for (int n = 0; n < 4; ++n) cy[n] = nB[colBase + wc * 64 + n * 16 + fr];
        #pragma unroll
        for (int m = 0; m < 4; ++m) bx[m] = *(const f32x4*)&nA[rowBase + wr * 64 + m * 16 + fq * 4];
        #pragma unroll
        for (int m = 0; m < 4; ++m)
            #pragma unroll
            for (int n = 0; n < 4; ++n) {
                float bc0 = cy[n];
                #pragma unroll
                for (int r = 0; r < 4; ++r) {
                    float arg = fmaf(acc[m][n][r], LOG2E, bx[m][r] + bc0);
                    float u = EXP2F(arg);       // v_exp_f32; underflows to 0 for far pairs
                    lsum = fmaf(u, u, lsum) + u;
                }
            }
    }
    #pragma unroll
    for (int o = 32; o > 0; o >>= 1) lsum += __shfl_xor(lsum, o, 64);
    if (lane == 0) red[wid] = lsum;
    __syncthreads();
    if (tid == 0) parts[bid] = wgt * (red[0] + red[1] + red[2] + red[3]);
}

// ---------------- kernel 3: final deterministic reduction
__global__ void reduce_parts(const float* __restrict__ parts, float* __restrict__ out) {
    __shared__ float buf[256];
    float s = 0.0f;
    for (int i = threadIdx.x; i < NT_TOT; i += 256) s += parts[i];
    buf[threadIdx.x] = s;
    __syncthreads();
    #pragma unroll
    for (int st = 128; st > 0; st >>= 1) {
        if ((int)threadIdx.x < st) buf[threadIdx.x] += buf[threadIdx.x + st];
        __syncthreads();
    }
    if (threadIdx.x == 0) out[0] = buf[0] * (1.0f / 67108864.0f);  // /8192^2
}

extern "C" void kernel_launch(void* const* d_in, const int* in_sizes, int n_in,
                              void* d_out, int out_size, void* d_ws, size_t ws_size,
                              hipStream_t stream) {
    const float* src = (const float*)d_in[0];
    const float* tgt = (const float*)d_in[1];

    // ws layout: Sbf16 (4MB) | Tbf16 (4MB) | nS (32KB) | nT (32KB) | parts (33KB)
    char* w = (char*)d_ws;
    unsigned short* Sb = (unsigned short*)w;
    unsigned short* Tb = (unsigned short*)(w + (size_t)NR * D * 2);
    float* nS = (float*)(w + 2 * (size_t)NR * D * 2);
    float* nT = nS + NR;
    float* parts = nT + NR;

    hipLaunchKernelGGL(prep_kernel, dim3(NR * 2 / 4), dim3(256), 0, stream,
                       src, tgt, Sb, Tb, nS, nT);
    hipLaunchKernelGGL(mmd_tiles, dim3(NT_TOT), dim3(256), 0, stream,
                       Sb, Tb, nS, nT, parts);
    hipLaunchKernelGGL(reduce_parts, dim3(1), dim3(256), 0, stream,
                       parts, (float*)d_out);
}

// Round 2
// 101.594 us; speedup vs baseline: 1.0901x; 1.0901x over previous
//
#include <hip/hip_runtime.h>
#include <stdint.h>

#define NR 8192
#define D 256
#define LOG2E 1.4426950408889634f
#define BM 128
#define BK 64
#define NKT (D / BK)    // 4 K-steps
#define NT_SS 2080      // 64*65/2 lower-triangle tiles per symmetric block
#define NT_TOT 8256     // 2*2080 + 4096

typedef __attribute__((ext_vector_type(8))) short short8;
typedef __attribute__((ext_vector_type(4))) float f32x4;

#if __has_builtin(__builtin_amdgcn_exp2f)
#define EXP2F(x) __builtin_amdgcn_exp2f(x)
#else
#define EXP2F(x) exp2f(x)
#endif

typedef __attribute__((address_space(1))) const void gvoid;
typedef __attribute__((address_space(3))) void lvoid;

__device__ __forceinline__ void gload16(const void* g, void* l) {
    // async global->LDS, 16B/lane; LDS dest is wave-uniform base + lane*16
    __builtin_amdgcn_global_load_lds((gvoid*)(uintptr_t)g, (lvoid*)(uintptr_t)l,
                                     16, 0, 0);
}

__device__ __forceinline__ unsigned short f2bf(float f) {
    uint32_t u = __float_as_uint(f);
    u += 0x7fffu + ((u >> 16) & 1u);   // RNE; inputs are finite Gaussians, no NaN
    return (unsigned short)(u >> 16);
}
__device__ __forceinline__ float bf2f(unsigned short h) {
    return __uint_as_float(((uint32_t)h) << 16);
}

// ---------------- kernel 1: f32 -> bf16 copies + row norms (from bf16 values)
__global__ void prep_kernel(const float* __restrict__ src, const float* __restrict__ tgt,
                            unsigned short* __restrict__ Sb, unsigned short* __restrict__ Tb,
                            float* __restrict__ nS, float* __restrict__ nT) {
    int wid = threadIdx.x >> 6, lane = threadIdx.x & 63;
    int row = blockIdx.x * 4 + wid;            // 0..16383
    const float* in; unsigned short* ob; float* on; int r;
    if (row < NR) { in = src; ob = Sb; on = nS; r = row; }
    else         { in = tgt; ob = Tb; on = nT; r = row - NR; }

    const float4* inr = (const float4*)(in + (size_t)r * D);
    float4 v = inr[lane];                       // 256 cols / 64 lanes = 4 f32
    unsigned short b0 = f2bf(v.x), b1 = f2bf(v.y), b2 = f2bf(v.z), b3 = f2bf(v.w);
    float f0 = bf2f(b0), f1 = bf2f(b1), f2 = bf2f(b2), f3 = bf2f(b3);
    float sq = f0 * f0 + f1 * f1 + f2 * f2 + f3 * f3;

    ushort4 pack = make_ushort4(b0, b1, b2, b3);
    *(ushort4*)(ob + (size_t)r * D + lane * 4) = pack;

    #pragma unroll
    for (int o = 32; o > 0; o >>= 1) sq += __shfl_xor(sq, o, 64);
    if (lane == 0) on[r] = -0.5f * LOG2E * sq;  // b_i = -(log2e/2)*||x_i||^2
}

// ---------------- kernel 2: fused tile GEMM + exp epilogue + tile reduction
// LDS layout: As/Bs [2 bufs][128 rows][64 elems] bf16, 128 B rows.
// XOR swizzle: LDS[row][16B-slot s] holds global data (row, s ^ (row&7)).
// global_load_lds writes linearly, so the per-lane GLOBAL source address
// carries the inverse permutation (rule: both-sides-or-neither).
__global__ __launch_bounds__(256) void mmd_tiles(
    const unsigned short* __restrict__ Sb, const unsigned short* __restrict__ Tb,
    const float* __restrict__ nS, const float* __restrict__ nT,
    float* __restrict__ parts)
{
    __shared__ unsigned short As[2][BM][BK];   // 2 x 16 KB
    __shared__ unsigned short Bs[2][BM][BK];   // 2 x 16 KB
    __shared__ float red[4];

    int bid = blockIdx.x;
    const unsigned short *Ab, *Bb; const float *nA, *nB; float wgt;
    int ti, tj;
    {
        int idx = bid;
        if (bid < 2 * NT_SS) {
            if (bid >= NT_SS) idx -= NT_SS;
            int t = (int)((sqrtf(8.0f * (float)idx + 1.0f) - 1.0f) * 0.5f);
            while ((t + 1) * (t + 2) / 2 <= idx) ++t;
            while (t * (t + 1) / 2 > idx) --t;
            ti = t; tj = idx - t * (t + 1) / 2;          // tj <= ti
            if (bid < NT_SS) { Ab = Sb; Bb = Sb; nA = nS; nB = nS; }
            else             { Ab = Tb; Bb = Tb; nA = nT; nB = nT; }
            wgt = (ti == tj) ? 1.0f : 2.0f;              // symmetric double-count
        } else {
            idx = bid - 2 * NT_SS;
            ti = idx >> 6; tj = idx & 63;
            Ab = Sb; Bb = Tb; nA = nS; nB = nT;
            wgt = -2.0f;                                  // -2 * mean(s,t)
        }
    }
    const int rowBase = ti * BM, colBase = tj * BM;

    const int tid = threadIdx.x;
    const int wid = tid >> 6, lane = tid & 63;
    const int wr = wid >> 1, wc = wid & 1;               // 2x2 waves, 64x64 each

    // ---- staging addresses: one gload16 call covers 8 rows (64 lanes x 16B)
    // lane -> (row-in-chunk, swizzled 16B slot in the 128B row)
    const int srow = lane >> 3;                          // 0..7
    const int sslot = (lane & 7) ^ srow;                 // inverse swizzle on SOURCE
    const size_t laneOff = (size_t)srow * (D * 2) + (size_t)sslot * 16;
    const char* Agp = (const char*)(Ab + (size_t)rowBase * D);
    const char* Bgp = (const char*)(Bb + (size_t)colBase * D);

    // ---- fragment read offsets (elements); logical k-slot q -> phys q^(fr&7)
    const int fr = lane & 15, hi = lane >> 4;
    const int swz0 = ((hi ^ (fr & 7)) * 8);              // ks=0: slots 0..3
    const int swz1 = (((4 + hi) ^ (fr & 7)) * 8);        // ks=1: slots 4..7

    f32x4 acc[4][4];
    #pragma unroll
    for (int m = 0; m < 4; ++m)
        #pragma unroll
        for (int n = 0; n < 4; ++n) acc[m][n] = (f32x4){0.f, 0.f, 0.f, 0.f};

    #define STAGE(buf, kt)                                                      \
        do {                                                                    \
            const char* ag = Agp + (size_t)(kt) * (BK * 2) + laneOff;           \
            const char* bg = Bgp + (size_t)(kt) * (BK * 2) + laneOff;           \
            _Pragma("unroll")                                                   \
            for (int i_ = 0; i_ < 4; ++i_) {                                    \
                int c_ = wid * 4 + i_;               /* 8-row chunk 0..15 */    \
                gload16(ag + (size_t)c_ * 8 * (D * 2), &As[buf][c_ * 8][0]);    \
                gload16(bg + (size_t)c_ * 8 * (D * 2), &Bs[buf][c_ * 8][0]);    \
            }                                                                   \
        } while (0)

    STAGE(0, 0);
    __syncthreads();                          // vmcnt(0) drain + barrier

    for (int kt = 0; kt < NKT; ++kt) {
        const int cur = kt & 1;
        if (kt + 1 < NKT) STAGE(cur ^ 1, kt + 1);   // issue next-tile loads FIRST

        const unsigned short* Ap = &As[cur][0][0];
        const unsigned short* Bp = &Bs[cur][0][0];
        short8 af[2][4], bfv[2][4];
        #pragma unroll
        for (int m = 0; m < 4; ++m) {
            int r = (wr * 64 + m * 16 + fr) * BK;
            af[0][m] = *(const short8*)(Ap + r + swz0);
            af[1][m] = *(const short8*)(Ap + r + swz1);
        }
        #pragma unroll
        for (int n = 0; n < 4; ++n) {
            int r = (wc * 64 + n * 16 + fr) * BK;
            bfv[0][n] = *(const short8*)(Bp + r + swz0);
            bfv[1][n] = *(const short8*)(Bp + r + swz1);
        }
        #pragma unroll
        for (int ks = 0; ks < 2; ++ks)
            #pragma unroll
            for (int m = 0; m < 4; ++m)
                #pragma unroll
                for (int n = 0; n < 4; ++n)
                    acc[m][n] = __builtin_amdgcn_mfma_f32_16x16x32_bf16(
                        af[ks][m], bfv[ks][n], acc[m][n], 0, 0, 0);
        __syncthreads();                      // one barrier per K-step
    }
    #undef STAGE

    // epilogue: u = exp(-l2/2) = exp2(log2e*xy + bx_i + cy_j); contrib = u + u^2
    float lsum = 0.0f;
    {
        const int fq = lane >> 4;
        float cy[4]; f32x4 bx[4];
        #pragma unroll
        for (int n = 0; n < 4; ++n) cy[n] = nB[colBase + wc * 64 + n * 16 + fr];
        #pragma unroll
        for (int m = 0; m < 4; ++m) bx[m] = *(const f32x4*)&nA[rowBase + wr * 64 + m * 16 + fq * 4];
        #pragma unroll
        for (int m = 0; m < 4; ++m)
            #pragma unroll
            for (int n = 0; n < 4; ++n) {
                float bc0 = cy[n];
                #pragma unroll
                for (int r = 0; r < 4; ++r) {
                    float arg = fmaf(acc[m][n][r], LOG2E, bx[m][r] + bc0);
                    float u = EXP2F(arg);       // v_exp_f32; underflows to 0 for far pairs
                    lsum = fmaf(u, u, lsum) + u;
                }
            }
    }
    #pragma unroll
    for (int o = 32; o > 0; o >>= 1) lsum += __shfl_xor(lsum, o, 64);
    if (lane == 0) red[wid] = lsum;
    __syncthreads();
    if (tid == 0) parts[bid] = wgt * (red[0] + red[1] + red[2] + red[3]);
}

// ---------------- kernel 3: final deterministic reduction
__global__ void reduce_parts(const float* __restrict__ parts, float* __restrict__ out) {
    __shared__ float buf[256];
    float s = 0.0f;
    for (int i = threadIdx.x; i < NT_TOT; i += 256) s += parts[i];
    buf[threadIdx.x] = s;
    __syncthreads();
    #pragma unroll
    for (int st = 128; st > 0; st >>= 1) {
        if ((int)threadIdx.x < st) buf[threadIdx.x] += buf[threadIdx.x + st];
        __syncthreads();
    }
    if (threadIdx.x == 0) out[0] = buf[0] * (1.0f / 67108864.0f);  // /8192^2
}

extern "C" void kernel_launch(void* const* d_in, const int* in_sizes, int n_in,
                              void* d_out, int out_size, void* d_ws, size_t ws_size,
                              hipStream_t stream) {
    const float* src = (const float*)d_in[0];
    const float* tgt = (const float*)d_in[1];

    // ws layout: Sbf16 (4MB) | Tbf16 (4MB) | nS (32KB) | nT (32KB) | parts (33KB)
    char* w = (char*)d_ws;
    unsigned short* Sb = (unsigned short*)w;
    unsigned short* Tb = (unsigned short*)(w + (size_t)NR * D * 2);
    float* nS = (float*)(w + 2 * (size_t)NR * D * 2);
    float* nT = nS + NR;
    float* parts = nT + NR;

    hipLaunchKernelGGL(prep_kernel, dim3(NR * 2 / 4), dim3(256), 0, stream,
                       src, tgt, Sb, Tb, nS, nT);
    hipLaunchKernelGGL(mmd_tiles, dim3(NT_TOT), dim3(256), 0, stream,
                       Sb, Tb, nS, nT, parts);
    hipLaunchKernelGGL(reduce_parts, dim3(1), dim3(256), 0, stream,
                       parts, (float*)d_out);
}